// Round 16
// baseline (226.953 us; speedup 1.0000x reference)
//
#include <hip/hip_runtime.h>
#include <hip/hip_bf16.h>
#include <stdint.h>

typedef __attribute__((ext_vector_type(8))) short bf16x8;
typedef __attribute__((ext_vector_type(8))) unsigned short u16x8;
typedef __attribute__((ext_vector_type(4))) float f32x4;
typedef __attribute__((ext_vector_type(4))) unsigned short u16x4;
typedef unsigned short u16;

// async global->LDS, 16B per lane. LDS dest must be wave-uniform base (+lane*16).
#define GLD16(g, l) __builtin_amdgcn_global_load_lds( \
    (const __attribute__((address_space(1))) unsigned int*)(g), \
    (__attribute__((address_space(3))) unsigned int*)(l), 16, 0, 0)

__device__ __forceinline__ u16 f2bf(float f) {
  union { __hip_bfloat16 h; u16 u; } cv;
  cv.h = __float2bfloat16(f);
  return cv.u;
}

// ---------------------------------------------------------------------------
// weight transpose + convert: wT[n][k] = bf16(w[k][n]). grid (16,16,4)
// ---------------------------------------------------------------------------
__global__ __launch_bounds__(256) void transw_kernel(
    const float* __restrict__ w0, const float* __restrict__ w1,
    const float* __restrict__ w2, const float* __restrict__ w3,
    u16* __restrict__ o0, u16* __restrict__ o1,
    u16* __restrict__ o2, u16* __restrict__ o3) {
  __shared__ float t[64][65];  // +1 pad: conflict-free transposed read
  const int z = blockIdx.z;
  const float* w = (z == 0) ? w0 : (z == 1) ? w1 : (z == 2) ? w2 : w3;
  u16* o = (z == 0) ? o0 : (z == 1) ? o1 : (z == 2) ? o2 : o3;
  const int bi = blockIdx.x * 64, bj = blockIdx.y * 64;
  const int c = threadIdx.x & 63, r0 = threadIdx.x >> 6;
#pragma unroll
  for (int i = 0; i < 16; i++) {
    int r = r0 + i * 4;
    t[r][c] = w[(size_t)(bi + r) * 1024 + bj + c];
  }
  __syncthreads();
#pragma unroll
  for (int i = 0; i < 16; i++) {
    int r = r0 + i * 4;
    o[(size_t)(bj + r) * 1024 + bi + c] = f2bf(t[c][r]);
  }
}

// ---------------------------------------------------------------------------
// V transpose: Vh [b*2048+s][h*64+d] -> Vt [(b*16+h)*64+d][s].
// 64x64 u16 tiles via LDS, pad-66 rows. grid (32 s-tiles, 32 bh).
// ---------------------------------------------------------------------------
__global__ __launch_bounds__(256) void transv_kernel(
    const u16* __restrict__ Vh, u16* __restrict__ Vt) {
  __shared__ u16 t[64 * 66];
  const int st = blockIdx.x, bh = blockIdx.y;
  const int b = bh >> 4, h = bh & 15;
  const int tid = threadIdx.x;
#pragma unroll
  for (int i = 0; i < 2; i++) {
    int c = i * 256 + tid;
    int row = c >> 3, col8 = c & 7;
    u16x8 v = *(const u16x8*)(Vh +
                              (size_t)(b * 2048 + st * 64 + row) * 1024 +
                              h * 64 + col8 * 8);
#pragma unroll
    for (int m = 0; m < 4; m++) {
      uint32_t p = (uint32_t)v[2 * m] | ((uint32_t)v[2 * m + 1] << 16);
      *(uint32_t*)&t[row * 66 + col8 * 8 + 2 * m] = p;
    }
  }
  __syncthreads();
#pragma unroll
  for (int i = 0; i < 2; i++) {
    int c = i * 256 + tid;
    int d = c >> 3, s8 = c & 7;
    u16x8 v;
#pragma unroll
    for (int k = 0; k < 8; k++) v[k] = t[(s8 * 8 + k) * 66 + d];
    *(u16x8*)(Vt + (size_t)((b * 16 + h) * 64 + d) * 2048 + st * 64 +
              s8 * 8) = v;
  }
}

// ---------------------------------------------------------------------------
// shared GEMM mainloop (bf16 A): C[128x128] = A[M][1024] @ Bt[1024][1024]^T
// ---------------------------------------------------------------------------
static __device__ __forceinline__ void gemm_mainloop(
    const u16* __restrict__ A, const u16* __restrict__ Bt, int bm, int bn,
    u16* Ash, u16* Bsh, f32x4 (&acc)[4][4]) {
  const int tid = threadIdx.x;
  const int wave = tid >> 6, lane = tid & 63;
  const int wm = (wave >> 1) * 64, wn = (wave & 1) * 64;
  const f32x4 vzero = {0.f, 0.f, 0.f, 0.f};
#pragma unroll
  for (int mi = 0; mi < 4; mi++)
#pragma unroll
    for (int ni = 0; ni < 4; ni++) acc[mi][ni] = vzero;

  for (int k0 = 0; k0 < 1024; k0 += 64) {
    __syncthreads();
#pragma unroll
    for (int i = 0; i < 4; i++) {
      int t = i * 256 + tid;
      int row = t >> 3;
      int colb = ((t & 7) * 16) ^ ((row & 7) << 4);
      GLD16((const char*)A + ((size_t)(bm + row) * 1024 + k0) * 2 + colb,
            (char*)Ash + (i * 256 + wave * 64) * 16);
    }
#pragma unroll
    for (int i = 0; i < 4; i++) {
      int t = i * 256 + tid;
      int row = t >> 3;
      int colb = ((t & 7) * 16) ^ ((row & 7) << 4);
      GLD16((const char*)Bt + ((size_t)(bn + row) * 1024 + k0) * 2 + colb,
            (char*)Bsh + (i * 256 + wave * 64) * 16);
    }
    __syncthreads();
#pragma unroll
    for (int kk = 0; kk < 2; kk++) {
      const int d0 = kk * 32 + (lane >> 4) * 8;
      bf16x8 af[4], bv[4];
#pragma unroll
      for (int mi = 0; mi < 4; mi++) {
        int r = wm + mi * 16 + (lane & 15);
        af[mi] = *(const bf16x8*)((const char*)Ash + r * 128 +
                                  ((d0 * 2) ^ ((r & 7) << 4)));
      }
#pragma unroll
      for (int ni = 0; ni < 4; ni++) {
        int r = wn + ni * 16 + (lane & 15);
        bv[ni] = *(const bf16x8*)((const char*)Bsh + r * 128 +
                                  ((d0 * 2) ^ ((r & 7) << 4)));
      }
#pragma unroll
      for (int mi = 0; mi < 4; mi++)
#pragma unroll
        for (int ni = 0; ni < 4; ni++)
          acc[mi][ni] = __builtin_amdgcn_mfma_f32_16x16x32_bf16(
              af[mi], bv[ni], acc[mi][ni], 0, 0, 0);
    }
  }
}

// ---------------------------------------------------------------------------
// fused q/k/v projection GEMM with INLINE f32->bf16 A staging (convert kernel
// deleted). A is read f32 from the original q/k/v inputs: per k-step, each
// thread loads 8x float4 (coalesced 256B row segments), converts to bf16,
// and ds_writes 8B chunks directly to the SWIZZLED Ash address (reg-staging
// allows swizzled LDS dests; fragment reads unchanged). B staging: GLD16.
// grid (32, 8, 3); coalesced [4096][1024] epilogue (Vh; transv after).
// ---------------------------------------------------------------------------
__global__ __launch_bounds__(256) void proj3_kernel(
    const float* __restrict__ q_in, const float* __restrict__ k_in,
    const float* __restrict__ v_in, const u16* __restrict__ wqT,
    const u16* __restrict__ wkT, const u16* __restrict__ wvT,
    const float* __restrict__ bq, const float* __restrict__ bk,
    const float* __restrict__ bv, u16* __restrict__ Qh, u16* __restrict__ Kh,
    u16* __restrict__ Vh) {
  __shared__ u16 Ash[128 * 64], Bsh[128 * 64];
  const int z = blockIdx.z;
  const float* Af = (z == 0) ? q_in : (z == 1) ? k_in : v_in;
  const u16* Bt = (z == 0) ? wqT : (z == 1) ? wkT : wvT;
  const float* bias = (z == 0) ? bq : (z == 1) ? bk : bv;
  u16* o = (z == 0) ? Qh : (z == 1) ? Kh : Vh;
  const int bm = blockIdx.x * 128, bn = blockIdx.y * 128;
  const int tid = threadIdx.x, wave = tid >> 6, lane = tid & 63;
  const int wm = (wave >> 1) * 64, wn = (wave & 1) * 64;
  const f32x4 vzero = {0.f, 0.f, 0.f, 0.f};
  f32x4 acc[4][4];
#pragma unroll
  for (int mi = 0; mi < 4; mi++)
#pragma unroll
    for (int ni = 0; ni < 4; ni++) acc[mi][ni] = vzero;

  for (int k0 = 0; k0 < 1024; k0 += 64) {
    __syncthreads();
    // A: f32 -> bf16 reg-staged into swizzled Ash (8B chunks, conflict-free:
    // 16 lanes cover one row's 128B; XOR swizzle matches fragment reads)
#pragma unroll
    for (int i = 0; i < 8; i++) {
      int n = i * 256 + tid;
      int row = n >> 4, c16 = n & 15;
      float4 v = *(const float4*)(Af + (size_t)(bm + row) * 1024 + k0 +
                                  c16 * 4);
      u16x4 ov = {f2bf(v.x), f2bf(v.y), f2bf(v.z), f2bf(v.w)};
      *(u16x4*)((char*)Ash + ((row * 128 + c16 * 8) ^ ((row & 7) << 4))) = ov;
    }
    // B: GLD16 (swizzled global source, linear LDS dest)
#pragma unroll
    for (int i = 0; i < 4; i++) {
      int t = i * 256 + tid;
      int row = t >> 3;
      int colb = ((t & 7) * 16) ^ ((row & 7) << 4);
      GLD16((const char*)Bt + ((size_t)(bn + row) * 1024 + k0) * 2 + colb,
            (char*)Bsh + (i * 256 + wave * 64) * 16);
    }
    __syncthreads();  // drains lgkm (A ds_writes) + vmcnt (B GLD16)
#pragma unroll
    for (int kk = 0; kk < 2; kk++) {
      const int d0 = kk * 32 + (lane >> 4) * 8;
      bf16x8 af[4], bv[4];
#pragma unroll
      for (int mi = 0; mi < 4; mi++) {
        int r = wm + mi * 16 + (lane & 15);
        af[mi] = *(const bf16x8*)((const char*)Ash + r * 128 +
                                  ((d0 * 2) ^ ((r & 7) << 4)));
      }
#pragma unroll
      for (int ni = 0; ni < 4; ni++) {
        int r = wn + ni * 16 + (lane & 15);
        bv[ni] = *(const bf16x8*)((const char*)Bsh + r * 128 +
                                  ((d0 * 2) ^ ((r & 7) << 4)));
      }
#pragma unroll
      for (int mi = 0; mi < 4; mi++)
#pragma unroll
        for (int ni = 0; ni < 4; ni++)
          acc[mi][ni] = __builtin_amdgcn_mfma_f32_16x16x32_bf16(
              af[mi], bv[ni], acc[mi][ni], 0, 0, 0);
    }
  }

  // epilogue: coalesced [4096][1024] bf16 store
#pragma unroll
  for (int ni = 0; ni < 4; ni++) {
    int gn = bn + wn + ni * 16 + (lane & 15);
    float bb = bias[gn];
#pragma unroll
    for (int mi = 0; mi < 4; mi++) {
#pragma unroll
      for (int j = 0; j < 4; j++) {
        int gm = bm + wm + mi * 16 + (lane >> 4) * 4 + j;
        o[(size_t)gm * 1024 + gn] = f2bf(acc[mi][ni][j] + bb);
      }
    }
  }
}

// ---------------------------------------------------------------------------
// output GEMM: out = concat @ woT + wo_b, f32. grid (32, 8)
// ---------------------------------------------------------------------------
__global__ __launch_bounds__(256) void gemm_out_kernel(
    const u16* __restrict__ A, const u16* __restrict__ Bt,
    const float* __restrict__ bias, float* __restrict__ out) {
  __shared__ u16 Ash[128 * 64], Bsh[128 * 64];
  const int bm = blockIdx.x * 128, bn = blockIdx.y * 128;
  f32x4 acc[4][4];
  gemm_mainloop(A, Bt, bm, bn, Ash, Bsh, acc);
  const int lane = threadIdx.x & 63, wave = threadIdx.x >> 6;
  const int wm = (wave >> 1) * 64, wn = (wave & 1) * 64;
#pragma unroll
  for (int ni = 0; ni < 4; ni++) {
    int gn = bn + wn + ni * 16 + (lane & 15);
    float bb = bias[gn];
#pragma unroll
    for (int mi = 0; mi < 4; mi++) {
#pragma unroll
      for (int j = 0; j < 4; j++) {
        int gm = bm + wm + mi * 16 + (lane >> 4) * 4 + j;
        out[(size_t)gm * 1024 + gn] = acc[mi][ni][j] + bb;
      }
    }
  }
}

// ---------------------------------------------------------------------------
// causal attention — R11 config (best): one q-tile/block, grid 1024 (3
// blocks/CU -> LPT backfill works; 4/CU kills backfill), dbuf prefetch, f32 P
// staging in LDS, coalesced NT attn stores (NT required: plain stores thrash
// L2), counted-vmcnt barrier in pass B, NT zero-fill tail.
// ---------------------------------------------------------------------------
__global__ __launch_bounds__(256) void attn_kernel(
    const u16* __restrict__ Qh, const u16* __restrict__ Kh,
    const u16* __restrict__ Vt, float* __restrict__ attn,
    u16* __restrict__ concat) {
  const int bid = blockIdx.x;
  const int xcd = bid & 7;
  const int r = bid >> 3;              // 0..127 within XCD, ~dispatch order
  const int qt = 31 - (r & 31);        // LPT: largest q-tiles first
  const int hb = xcd * 4 + (r >> 5);   // 4 (b,h) pairs per XCD
  const int h = hb & 15, b = hb >> 4;
  const int tid = threadIdx.x, wave = tid >> 6, lane = tid & 63;
  const int l15 = lane & 15, lhi = lane >> 4;
  const f32x4 vzero = {0.f, 0.f, 0.f, 0.f};

  __shared__ u16 Ksh[2][64 * 64], Vsh[2][64 * 64];
  __shared__ float Psf[4][1024];  // per-wave 16x64 f32, XOR-swizzled
  char* Pwc = (char*)Psf[wave];

  const u16* Kbase = Kh + (size_t)(b * 2048) * 1024 + h * 64;
  const u16* Vbase = Vt + (size_t)(b * 16 + h) * 64 * 2048;
  float* attn_bh = attn + (size_t)(b * 16 + h) * 2048 * 2048;

  auto stageK = [&](u16* dst, int kt) {
#pragma unroll
    for (int i = 0; i < 2; i++) {
      int t = i * 256 + tid;
      int row = t >> 3;
      int colb = ((t & 7) * 16) ^ ((row & 7) << 4);
      GLD16((const char*)(Kbase + (size_t)(kt * 64 + row) * 1024) + colb,
            (char*)dst + (i * 256 + wave * 64) * 16);
    }
  };
  auto stageV = [&](u16* dst, int kt) {
#pragma unroll
    for (int i = 0; i < 2; i++) {
      int t = i * 256 + tid;
      int row = t >> 3;
      int colb = ((t & 7) * 16) ^ ((row & 7) << 4);
      GLD16((const char*)(Vbase + (size_t)row * 2048 + kt * 64) + colb,
            (char*)dst + (i * 256 + wave * 64) * 16);
    }
  };
  auto qkt = [&](const u16* Kbuf, const bf16x8* qf, f32x4* sacc) {
#pragma unroll
    for (int ni = 0; ni < 4; ni++) sacc[ni] = vzero;
    __builtin_amdgcn_s_setprio(1);
#pragma unroll
    for (int kk = 0; kk < 2; kk++) {
      const int d0 = kk * 32 + lhi * 8;
#pragma unroll
      for (int ni = 0; ni < 4; ni++) {
        int r2 = ni * 16 + l15;
        bf16x8 kf = *(const bf16x8*)((const char*)Kbuf + r2 * 128 +
                                     ((d0 * 2) ^ ((r2 & 7) << 4)));
        sacc[ni] = __builtin_amdgcn_mfma_f32_16x16x32_bf16(qf[kk], kf,
                                                           sacc[ni], 0, 0, 0);
      }
    }
    __builtin_amdgcn_s_setprio(0);
  };

  const u16* Qrow =
      Qh + (size_t)(b * 2048 + qt * 64 + wave * 16 + l15) * 1024 + h * 64;
  bf16x8 qf[2];
  qf[0] = *(const bf16x8*)(Qrow + lhi * 8);
  qf[1] = *(const bf16x8*)(Qrow + 32 + lhi * 8);

  // ---- pass A: row sums (double-buffered K prefetch) ----
  float srow[4] = {0.f, 0.f, 0.f, 0.f};
  stageK(Ksh[0], 0);
  __syncthreads();  // drains vmcnt
  int cur = 0;
  for (int kt = 0; kt <= qt; kt++) {
    if (kt < qt) stageK(Ksh[cur ^ 1], kt + 1);
    f32x4 sacc[4];
    qkt(Ksh[cur], qf, sacc);
#pragma unroll
    for (int j = 0; j < 4; j++) {
      const int gi = qt * 64 + wave * 16 + lhi * 4 + j;
      float ps = 0.f;
#pragma unroll
      for (int ni = 0; ni < 4; ni++) {
        int gj = kt * 64 + ni * 16 + l15;
        float l = fminf(sacc[ni][j] * 0.125f, 60.f);
        ps += (gj > gi) ? 0.f : __expf(l);
      }
#pragma unroll
      for (int dd = 1; dd < 16; dd <<= 1) ps += __shfl_xor(ps, dd, 16);
      srow[j] += ps;
    }
    __syncthreads();  // prefetch landed + all waves done with Ksh[cur]
    cur ^= 1;
  }
  float rs[4];
#pragma unroll
  for (int j = 0; j < 4; j++) rs[j] = 1.0f / srow[j];

  // ---- pass B: recompute, stage P in LDS, coalesced attn store, PV ----
  f32x4 ctx[4];
#pragma unroll
  for (int ni = 0; ni < 4; ni++) ctx[ni] = vzero;
  stageK(Ksh[0], 0);
  stageV(Vsh[0], 0);
  __syncthreads();
  cur = 0;
  for (int kt = 0; kt <= qt; kt++) {
    if (kt < qt) {
      stageK(Ksh[cur ^ 1], kt + 1);  // 2 GLD16
      stageV(Vsh[cur ^ 1], kt + 1);  // 2 GLD16
    }
    f32x4 sacc[4];
    qkt(Ksh[cur], qf, sacc);
    // softmax -> P staged to per-wave f32 LDS (swizzled)
#pragma unroll
    for (int j = 0; j < 4; j++) {
      const int riw = lhi * 4 + j;
      const int gi = qt * 64 + wave * 16 + riw;
#pragma unroll
      for (int ni = 0; ni < 4; ni++) {
        const int cj = ni * 16 + l15;
        const int gj = kt * 64 + cj;
        float l = fminf(sacc[ni][j] * 0.125f, 60.f);
        float p = (gj > gi) ? 0.f : __expf(l) * rs[j];
        *(float*)(Pwc + ((riw * 256 + cj * 4) ^ ((riw & 7) << 4))) = p;
      }
    }
    // intra-wave only: P writes must land before reads
    asm volatile("s_waitcnt lgkmcnt(0)" ::: "memory");
    __builtin_amdgcn_sched_barrier(0);
    // coalesced attn store: 4 dwordx4 NT stores, 256B/row segments
#pragma unroll
    for (int s = 0; s < 4; s++) {
      const int row = s * 4 + lhi;
      const int gi = qt * 64 + wave * 16 + row;
      f32x4 pv4 =
          *(const f32x4*)(Pwc + ((row * 256 + l15 * 16) ^ ((row & 7) << 4)));
      __builtin_nontemporal_store(
          pv4, (f32x4*)(attn_bh + (size_t)gi * 2048 + kt * 64 + l15 * 4));
    }
    // PV: read P rows from f32 LDS, convert to bf16 in-register
    __builtin_amdgcn_s_setprio(1);
#pragma unroll
    for (int kk = 0; kk < 2; kk++) {
      const int s0 = kk * 32 + lhi * 8;
      f32x4 pa = *(const f32x4*)(Pwc +
                                 ((l15 * 256 + s0 * 4) ^ ((l15 & 7) << 4)));
      f32x4 pb = *(const f32x4*)(
          Pwc + ((l15 * 256 + s0 * 4 + 16) ^ ((l15 & 7) << 4)));
      bf16x8 pf;
      pf[0] = (short)f2bf(pa.x); pf[1] = (short)f2bf(pa.y);
      pf[2] = (short)f2bf(pa.z); pf[3] = (short)f2bf(pa.w);
      pf[4] = (short)f2bf(pb.x); pf[5] = (short)f2bf(pb.y);
      pf[6] = (short)f2bf(pb.z); pf[7] = (short)f2bf(pb.w);
#pragma unroll
      for (int ni = 0; ni < 4; ni++) {
        int vr = ni * 16 + l15;
        bf16x8 vf = *(const bf16x8*)((const char*)Vsh[cur] + vr * 128 +
                                     ((s0 * 2) ^ ((vr & 7) << 4)));
        ctx[ni] = __builtin_amdgcn_mfma_f32_16x16x32_bf16(pf, vf, ctx[ni],
                                                          0, 0, 0);
      }
    }
    __builtin_amdgcn_s_setprio(0);
    // counted barrier: wait only the 4 prefetch loads (oldest in-order);
    // the 4 attn stores (issued after them) may stay in flight.
    asm volatile("s_waitcnt vmcnt(4) lgkmcnt(0)" ::: "memory");
    __builtin_amdgcn_sched_barrier(0);
    __builtin_amdgcn_s_barrier();
    cur ^= 1;
  }

  // ctx -> concat (bf16, standard [4096][1024] layout)
#pragma unroll
  for (int ni = 0; ni < 4; ni++) {
#pragma unroll
    for (int j = 0; j < 4; j++) {
      int gm = b * 2048 + qt * 64 + wave * 16 + lhi * 4 + j;
      int gn = h * 64 + ni * 16 + l15;
      concat[(size_t)gm * 1024 + gn] = f2bf(ctx[ni][j]);
    }
  }

  // zero-fill strictly-upper attn tiles for these 64 rows (nontemporal)
  const int zc0 = (qt + 1) * 64;
  if (zc0 < 2048) {
    const f32x4 z4 = {0.f, 0.f, 0.f, 0.f};
    const int W4 = (2048 - zc0) >> 2;
    f32x4* rowbase = (f32x4*)(attn_bh + (size_t)(qt * 64) * 2048 + zc0);
    for (int rr = 0; rr < 64; rr++) {
      f32x4* rp = rowbase + (size_t)rr * 512;
      for (int cc = tid; cc < W4; cc += 256)
        __builtin_nontemporal_store(z4, &rp[cc]);
    }
  }
}

// ---------------------------------------------------------------------------
extern "C" void kernel_launch(void* const* d_in, const int* in_sizes, int n_in,
                              void* d_out, int out_size, void* d_ws,
                              size_t ws_size, hipStream_t stream) {
  const float* k_in = (const float*)d_in[0];
  const float* v_in = (const float*)d_in[1];
  const float* q_in = (const float*)d_in[2];
  // d_in[3] = mask (unused; causality computed arithmetically)
  const float* wq_w = (const float*)d_in[4];
  const float* wq_b = (const float*)d_in[5];
  const float* wk_w = (const float*)d_in[6];
  const float* wk_b = (const float*)d_in[7];
  const float* wv_w = (const float*)d_in[8];
  const float* wv_b = (const float*)d_in[9];
  const float* wo_w = (const float*)d_in[10];
  const float* wo_b = (const float*)d_in[11];

  char* ws = (char*)d_ws;
  u16* wqT = (u16*)(ws + ((size_t)24 << 20));
  u16* wkT = (u16*)(ws + ((size_t)26 << 20));
  u16* wvT = (u16*)(ws + ((size_t)28 << 20));
  u16* woT = (u16*)(ws + ((size_t)30 << 20));
  u16* Qh = (u16*)(ws + ((size_t)32 << 20));
  u16* Kh = (u16*)(ws + ((size_t)40 << 20));
  u16* Vt = (u16*)(ws + ((size_t)48 << 20));
  // Vh (proj3 output, [s][d] layout) and concat SHARE 56-64 MB: Vh is dead
  // after transv (pre-attn); attn then writes concat there. Stream-ordered.
  u16* Vh = (u16*)(ws + ((size_t)56 << 20));
  u16* concat = (u16*)(ws + ((size_t)56 << 20));

  float* outp = (float*)d_out;
  float* attnp = outp + (size_t)2 * 2048 * 1024;  // tuple elem 1

  transw_kernel<<<dim3(16, 16, 4), dim3(256), 0, stream>>>(
      wq_w, wk_w, wv_w, wo_w, wqT, wkT, wvT, woT);
  proj3_kernel<<<dim3(32, 8, 3), dim3(256), 0, stream>>>(
      q_in, k_in, v_in, wqT, wkT, wvT, wq_b, wk_b, wv_b, Qh, Kh, Vh);
  transv_kernel<<<dim3(32, 32), dim3(256), 0, stream>>>(Vh, Vt);
  attn_kernel<<<dim3(1024), dim3(256), 0, stream>>>(Qh, Kh, Vt, attnp, concat);
  gemm_out_kernel<<<dim3(32, 8), dim3(256), 0, stream>>>(concat, woT, wo_b,
                                                         outp);
}

// Round 18
// 220.466 us; speedup vs baseline: 1.0294x; 1.0294x over previous
//
#include <hip/hip_runtime.h>
#include <hip/hip_bf16.h>
#include <stdint.h>

typedef __attribute__((ext_vector_type(8))) short bf16x8;
typedef __attribute__((ext_vector_type(8))) unsigned short u16x8;
typedef __attribute__((ext_vector_type(4))) float f32x4;
typedef __attribute__((ext_vector_type(4))) unsigned short u16x4;
typedef unsigned short u16;

// async global->LDS, 16B per lane. LDS dest must be wave-uniform base (+lane*16).
#define GLD16(g, l) __builtin_amdgcn_global_load_lds( \
    (const __attribute__((address_space(1))) unsigned int*)(g), \
    (__attribute__((address_space(3))) unsigned int*)(l), 16, 0, 0)

__device__ __forceinline__ u16 f2bf(float f) {
  union { __hip_bfloat16 h; u16 u; } cv;
  cv.h = __float2bfloat16(f);
  return cv.u;
}

// ---------------------------------------------------------------------------
// f32 -> bf16 convert for q,k,v activations. grid (blocks, 3)
// ---------------------------------------------------------------------------
__global__ __launch_bounds__(256) void convert_kernel(
    const float* __restrict__ s0, const float* __restrict__ s1,
    const float* __restrict__ s2,
    u16* __restrict__ d0, u16* __restrict__ d1, u16* __restrict__ d2) {
  const int z = blockIdx.y;
  const float* s = (z == 0) ? s0 : (z == 1) ? s1 : s2;
  u16* d = (z == 0) ? d0 : (z == 1) ? d1 : d2;
  const int n4 = (2 * 2048 * 1024) / 4;
  for (int i = blockIdx.x * 256 + threadIdx.x; i < n4; i += gridDim.x * 256) {
    float4 v = ((const float4*)s)[i];
    u16x4 o = {f2bf(v.x), f2bf(v.y), f2bf(v.z), f2bf(v.w)};
    ((u16x4*)d)[i] = o;
  }
}

// ---------------------------------------------------------------------------
// weight transpose + convert: wT[n][k] = bf16(w[k][n]). grid (16,16,4)
// ---------------------------------------------------------------------------
__global__ __launch_bounds__(256) void transw_kernel(
    const float* __restrict__ w0, const float* __restrict__ w1,
    const float* __restrict__ w2, const float* __restrict__ w3,
    u16* __restrict__ o0, u16* __restrict__ o1,
    u16* __restrict__ o2, u16* __restrict__ o3) {
  __shared__ float t[64][65];  // +1 pad: conflict-free transposed read
  const int z = blockIdx.z;
  const float* w = (z == 0) ? w0 : (z == 1) ? w1 : (z == 2) ? w2 : w3;
  u16* o = (z == 0) ? o0 : (z == 1) ? o1 : (z == 2) ? o2 : o3;
  const int bi = blockIdx.x * 64, bj = blockIdx.y * 64;
  const int c = threadIdx.x & 63, r0 = threadIdx.x >> 6;
#pragma unroll
  for (int i = 0; i < 16; i++) {
    int r = r0 + i * 4;
    t[r][c] = w[(size_t)(bi + r) * 1024 + bj + c];
  }
  __syncthreads();
#pragma unroll
  for (int i = 0; i < 16; i++) {
    int r = r0 + i * 4;
    o[(size_t)(bj + r) * 1024 + bi + c] = f2bf(t[c][r]);
  }
}

// ---------------------------------------------------------------------------
// shared GEMM mainloop: C[128x128] = A[M][1024] @ Bt[1024][1024]^T-rows
// ---------------------------------------------------------------------------
static __device__ __forceinline__ void gemm_mainloop(
    const u16* __restrict__ A, const u16* __restrict__ Bt, int bm, int bn,
    u16* Ash, u16* Bsh, f32x4 (&acc)[4][4]) {
  const int tid = threadIdx.x;
  const int wave = tid >> 6, lane = tid & 63;
  const int wm = (wave >> 1) * 64, wn = (wave & 1) * 64;
  const f32x4 vzero = {0.f, 0.f, 0.f, 0.f};
#pragma unroll
  for (int mi = 0; mi < 4; mi++)
#pragma unroll
    for (int ni = 0; ni < 4; ni++) acc[mi][ni] = vzero;

  for (int k0 = 0; k0 < 1024; k0 += 64) {
    __syncthreads();
#pragma unroll
    for (int i = 0; i < 4; i++) {
      int t = i * 256 + tid;
      int row = t >> 3;
      int colb = ((t & 7) * 16) ^ ((row & 7) << 4);
      GLD16((const char*)A + ((size_t)(bm + row) * 1024 + k0) * 2 + colb,
            (char*)Ash + (i * 256 + wave * 64) * 16);
    }
#pragma unroll
    for (int i = 0; i < 4; i++) {
      int t = i * 256 + tid;
      int row = t >> 3;
      int colb = ((t & 7) * 16) ^ ((row & 7) << 4);
      GLD16((const char*)Bt + ((size_t)(bn + row) * 1024 + k0) * 2 + colb,
            (char*)Bsh + (i * 256 + wave * 64) * 16);
    }
    __syncthreads();
#pragma unroll
    for (int kk = 0; kk < 2; kk++) {
      const int d0 = kk * 32 + (lane >> 4) * 8;
      bf16x8 af[4], bv[4];
#pragma unroll
      for (int mi = 0; mi < 4; mi++) {
        int r = wm + mi * 16 + (lane & 15);
        af[mi] = *(const bf16x8*)((const char*)Ash + r * 128 +
                                  ((d0 * 2) ^ ((r & 7) << 4)));
      }
#pragma unroll
      for (int ni = 0; ni < 4; ni++) {
        int r = wn + ni * 16 + (lane & 15);
        bv[ni] = *(const bf16x8*)((const char*)Bsh + r * 128 +
                                  ((d0 * 2) ^ ((r & 7) << 4)));
      }
#pragma unroll
      for (int mi = 0; mi < 4; mi++)
#pragma unroll
        for (int ni = 0; ni < 4; ni++)
          acc[mi][ni] = __builtin_amdgcn_mfma_f32_16x16x32_bf16(
              af[mi], bv[ni], acc[mi][ni], 0, 0, 0);
    }
  }
}

// ---------------------------------------------------------------------------
// fused q/k/v projection GEMM. grid (32, 8, 3). z=0/1: coalesced [4096][1024]
// epilogue to Qh/Kh. z=2: C-tile transposed through a 34KB LDS buffer
// (aliased over Ash/Bsh, dead post-mainloop) and written DIRECTLY to
// Vt [(b*16+h)*64+d][s] as 256B-contiguous segments (replaces transv).
// R18 fix: s-coordinate is bm&2047 (bm includes the b*2048 batch offset).
// ---------------------------------------------------------------------------
__global__ __launch_bounds__(256) void proj3_kernel(
    const u16* __restrict__ xq, const u16* __restrict__ xk,
    const u16* __restrict__ xv, const u16* __restrict__ wqT,
    const u16* __restrict__ wkT, const u16* __restrict__ wvT,
    const float* __restrict__ bq, const float* __restrict__ bk,
    const float* __restrict__ bv, u16* __restrict__ Qh, u16* __restrict__ Kh,
    u16* __restrict__ Vt) {
  __shared__ char smem[34816];  // mainloop: Ash(16K)+Bsh(16K); epi: T 128x136
  u16* Ash = (u16*)smem;
  u16* Bsh = Ash + 8192;
  const int z = blockIdx.z;
  const u16* A = (z == 0) ? xq : (z == 1) ? xk : xv;
  const u16* Bt = (z == 0) ? wqT : (z == 1) ? wkT : wvT;
  const float* bias = (z == 0) ? bq : (z == 1) ? bk : bv;
  const int bm = blockIdx.x * 128, bn = blockIdx.y * 128;
  const int tid = threadIdx.x, wave = tid >> 6, lane = tid & 63;
  const int l15 = lane & 15, lhi = lane >> 4;
  const int wm = (wave >> 1) * 64, wn = (wave & 1) * 64;
  f32x4 acc[4][4];
  gemm_mainloop(A, Bt, bm, bn, Ash, Bsh, acc);

  if (z < 2) {
    u16* o = (z == 0) ? Qh : Kh;
#pragma unroll
    for (int ni = 0; ni < 4; ni++) {
      int gn = bn + wn + ni * 16 + l15;
      float bb = bias[gn];
#pragma unroll
      for (int mi = 0; mi < 4; mi++) {
#pragma unroll
        for (int j = 0; j < 4; j++) {
          int gm = bm + wm + mi * 16 + lhi * 4 + j;
          o[(size_t)gm * 1024 + gn] = f2bf(acc[mi][ni][j] + bb);
        }
      }
    }
  } else {
    // ---- z==2: transpose C through LDS, write Vt coalesced ----
    __syncthreads();  // all waves done reading Ash/Bsh
    u16* T = (u16*)smem;  // [128 gn-rows][136 gm-cols] u16 (272B rows, 16B-al)
#pragma unroll
    for (int ni = 0; ni < 4; ni++) {
      int gnl = wn + ni * 16 + l15;
      float bb = bias[bn + gnl];
#pragma unroll
      for (int mi = 0; mi < 4; mi++) {
        int gml = wm + mi * 16 + lhi * 4;
        u16x4 ov = {f2bf(acc[mi][ni][0] + bb), f2bf(acc[mi][ni][1] + bb),
                    f2bf(acc[mi][ni][2] + bb), f2bf(acc[mi][ni][3] + bb)};
        *(u16x4*)((char*)T + gnl * 272 + gml * 2) = ov;
      }
    }
    __syncthreads();
    const int b = bm >> 11;       // batch of this block's 128 gm-rows
    const int s0 = bm & 2047;     // s-coordinate base (R18 fix)
#pragma unroll
    for (int i = 0; i < 8; i++) {
      int t = i * 256 + tid;
      int dl = t >> 4, c = t & 15;  // row gn-local, 16B chunk in s
      u16x8 v = *(const u16x8*)((const char*)T + dl * 272 + c * 16);
      *(u16x8*)(Vt + (size_t)(b * 1024 + bn + dl) * 2048 + s0 + c * 8) = v;
    }
  }
}

// ---------------------------------------------------------------------------
// output GEMM: out = concat @ woT + wo_b, f32. grid (32, 8)
// ---------------------------------------------------------------------------
__global__ __launch_bounds__(256) void gemm_out_kernel(
    const u16* __restrict__ A, const u16* __restrict__ Bt,
    const float* __restrict__ bias, float* __restrict__ out) {
  __shared__ u16 Ash[128 * 64], Bsh[128 * 64];
  const int bm = blockIdx.x * 128, bn = blockIdx.y * 128;
  f32x4 acc[4][4];
  gemm_mainloop(A, Bt, bm, bn, Ash, Bsh, acc);
  const int lane = threadIdx.x & 63, wave = threadIdx.x >> 6;
  const int wm = (wave >> 1) * 64, wn = (wave & 1) * 64;
#pragma unroll
  for (int ni = 0; ni < 4; ni++) {
    int gn = bn + wn + ni * 16 + (lane & 15);
    float bb = bias[gn];
#pragma unroll
    for (int mi = 0; mi < 4; mi++) {
#pragma unroll
      for (int j = 0; j < 4; j++) {
        int gm = bm + wm + mi * 16 + (lane >> 4) * 4 + j;
        out[(size_t)gm * 1024 + gn] = acc[mi][ni][j] + bb;
      }
    }
  }
}

// ---------------------------------------------------------------------------
// causal attention — R11/R15 config (best: 224.6 us): one q-tile/block, grid
// 1024 (3 blocks/CU -> LPT backfill; 4/CU kills it), dbuf prefetch, f32 P
// staging in LDS, coalesced NT attn stores (NT required), counted-vmcnt
// barrier in pass B, NT zero-fill tail.
// ---------------------------------------------------------------------------
__global__ __launch_bounds__(256) void attn_kernel(
    const u16* __restrict__ Qh, const u16* __restrict__ Kh,
    const u16* __restrict__ Vt, float* __restrict__ attn,
    u16* __restrict__ concat) {
  const int bid = blockIdx.x;
  const int xcd = bid & 7;
  const int r = bid >> 3;              // 0..127 within XCD, ~dispatch order
  const int qt = 31 - (r & 31);        // LPT: largest q-tiles first
  const int hb = xcd * 4 + (r >> 5);   // 4 (b,h) pairs per XCD
  const int h = hb & 15, b = hb >> 4;
  const int tid = threadIdx.x, wave = tid >> 6, lane = tid & 63;
  const int l15 = lane & 15, lhi = lane >> 4;
  const f32x4 vzero = {0.f, 0.f, 0.f, 0.f};

  __shared__ u16 Ksh[2][64 * 64], Vsh[2][64 * 64];
  __shared__ float Psf[4][1024];  // per-wave 16x64 f32, XOR-swizzled
  char* Pwc = (char*)Psf[wave];

  const u16* Kbase = Kh + (size_t)(b * 2048) * 1024 + h * 64;
  const u16* Vbase = Vt + (size_t)(b * 16 + h) * 64 * 2048;
  float* attn_bh = attn + (size_t)(b * 16 + h) * 2048 * 2048;

  auto stageK = [&](u16* dst, int kt) {
#pragma unroll
    for (int i = 0; i < 2; i++) {
      int t = i * 256 + tid;
      int row = t >> 3;
      int colb = ((t & 7) * 16) ^ ((row & 7) << 4);
      GLD16((const char*)(Kbase + (size_t)(kt * 64 + row) * 1024) + colb,
            (char*)dst + (i * 256 + wave * 64) * 16);
    }
  };
  auto stageV = [&](u16* dst, int kt) {
#pragma unroll
    for (int i = 0; i < 2; i++) {
      int t = i * 256 + tid;
      int row = t >> 3;
      int colb = ((t & 7) * 16) ^ ((row & 7) << 4);
      GLD16((const char*)(Vbase + (size_t)row * 2048 + kt * 64) + colb,
            (char*)dst + (i * 256 + wave * 64) * 16);
    }
  };
  auto qkt = [&](const u16* Kbuf, const bf16x8* qf, f32x4* sacc) {
#pragma unroll
    for (int ni = 0; ni < 4; ni++) sacc[ni] = vzero;
    __builtin_amdgcn_s_setprio(1);
#pragma unroll
    for (int kk = 0; kk < 2; kk++) {
      const int d0 = kk * 32 + lhi * 8;
#pragma unroll
      for (int ni = 0; ni < 4; ni++) {
        int r2 = ni * 16 + l15;
        bf16x8 kf = *(const bf16x8*)((const char*)Kbuf + r2 * 128 +
                                     ((d0 * 2) ^ ((r2 & 7) << 4)));
        sacc[ni] = __builtin_amdgcn_mfma_f32_16x16x32_bf16(qf[kk], kf,
                                                           sacc[ni], 0, 0, 0);
      }
    }
    __builtin_amdgcn_s_setprio(0);
  };

  const u16* Qrow =
      Qh + (size_t)(b * 2048 + qt * 64 + wave * 16 + l15) * 1024 + h * 64;
  bf16x8 qf[2];
  qf[0] = *(const bf16x8*)(Qrow + lhi * 8);
  qf[1] = *(const bf16x8*)(Qrow + 32 + lhi * 8);

  // ---- pass A: row sums (double-buffered K prefetch) ----
  float srow[4] = {0.f, 0.f, 0.f, 0.f};
  stageK(Ksh[0], 0);
  __syncthreads();  // drains vmcnt
  int cur = 0;
  for (int kt = 0; kt <= qt; kt++) {
    if (kt < qt) stageK(Ksh[cur ^ 1], kt + 1);
    f32x4 sacc[4];
    qkt(Ksh[cur], qf, sacc);
#pragma unroll
    for (int j = 0; j < 4; j++) {
      const int gi = qt * 64 + wave * 16 + lhi * 4 + j;
      float ps = 0.f;
#pragma unroll
      for (int ni = 0; ni < 4; ni++) {
        int gj = kt * 64 + ni * 16 + l15;
        float l = fminf(sacc[ni][j] * 0.125f, 60.f);
        ps += (gj > gi) ? 0.f : __expf(l);
      }
#pragma unroll
      for (int dd = 1; dd < 16; dd <<= 1) ps += __shfl_xor(ps, dd, 16);
      srow[j] += ps;
    }
    __syncthreads();  // prefetch landed + all waves done with Ksh[cur]
    cur ^= 1;
  }
  float rs[4];
#pragma unroll
  for (int j = 0; j < 4; j++) rs[j] = 1.0f / srow[j];

  // ---- pass B: recompute, stage P in LDS, coalesced attn store, PV ----
  f32x4 ctx[4];
#pragma unroll
  for (int ni = 0; ni < 4; ni++) ctx[ni] = vzero;
  stageK(Ksh[0], 0);
  stageV(Vsh[0], 0);
  __syncthreads();
  cur = 0;
  for (int kt = 0; kt <= qt; kt++) {
    if (kt < qt) {
      stageK(Ksh[cur ^ 1], kt + 1);  // 2 GLD16
      stageV(Vsh[cur ^ 1], kt + 1);  // 2 GLD16
    }
    f32x4 sacc[4];
    qkt(Ksh[cur], qf, sacc);
    // softmax -> P staged to per-wave f32 LDS (swizzled)
#pragma unroll
    for (int j = 0; j < 4; j++) {
      const int riw = lhi * 4 + j;
      const int gi = qt * 64 + wave * 16 + riw;
#pragma unroll
      for (int ni = 0; ni < 4; ni++) {
        const int cj = ni * 16 + l15;
        const int gj = kt * 64 + cj;
        float l = fminf(sacc[ni][j] * 0.125f, 60.f);
        float p = (gj > gi) ? 0.f : __expf(l) * rs[j];
        *(float*)(Pwc + ((riw * 256 + cj * 4) ^ ((riw & 7) << 4))) = p;
      }
    }
    // intra-wave only: P writes must land before reads
    asm volatile("s_waitcnt lgkmcnt(0)" ::: "memory");
    __builtin_amdgcn_sched_barrier(0);
    // coalesced attn store: 4 dwordx4 NT stores, 256B/row segments
#pragma unroll
    for (int s = 0; s < 4; s++) {
      const int row = s * 4 + lhi;
      const int gi = qt * 64 + wave * 16 + row;
      f32x4 pv4 =
          *(const f32x4*)(Pwc + ((row * 256 + l15 * 16) ^ ((row & 7) << 4)));
      __builtin_nontemporal_store(
          pv4, (f32x4*)(attn_bh + (size_t)gi * 2048 + kt * 64 + l15 * 4));
    }
    // PV: read P rows from f32 LDS, convert to bf16 in-register
    __builtin_amdgcn_s_setprio(1);
#pragma unroll
    for (int kk = 0; kk < 2; kk++) {
      const int s0 = kk * 32 + lhi * 8;
      f32x4 pa = *(const f32x4*)(Pwc +
                                 ((l15 * 256 + s0 * 4) ^ ((l15 & 7) << 4)));
      f32x4 pb = *(const f32x4*)(
          Pwc + ((l15 * 256 + s0 * 4 + 16) ^ ((l15 & 7) << 4)));
      bf16x8 pf;
      pf[0] = (short)f2bf(pa.x); pf[1] = (short)f2bf(pa.y);
      pf[2] = (short)f2bf(pa.z); pf[3] = (short)f2bf(pa.w);
      pf[4] = (short)f2bf(pb.x); pf[5] = (short)f2bf(pb.y);
      pf[6] = (short)f2bf(pb.z); pf[7] = (short)f2bf(pb.w);
#pragma unroll
      for (int ni = 0; ni < 4; ni++) {
        int vr = ni * 16 + l15;
        bf16x8 vf = *(const bf16x8*)((const char*)Vsh[cur] + vr * 128 +
                                     ((s0 * 2) ^ ((vr & 7) << 4)));
        ctx[ni] = __builtin_amdgcn_mfma_f32_16x16x32_bf16(pf, vf, ctx[ni],
                                                          0, 0, 0);
      }
    }
    __builtin_amdgcn_s_setprio(0);
    // counted barrier: wait only the 4 prefetch loads (oldest in-order);
    // the 4 attn stores (issued after them) may stay in flight.
    asm volatile("s_waitcnt vmcnt(4) lgkmcnt(0)" ::: "memory");
    __builtin_amdgcn_sched_barrier(0);
    __builtin_amdgcn_s_barrier();
    cur ^= 1;
  }

  // ctx -> concat (bf16, standard [4096][1024] layout)
#pragma unroll
  for (int ni = 0; ni < 4; ni++) {
#pragma unroll
    for (int j = 0; j < 4; j++) {
      int gm = b * 2048 + qt * 64 + wave * 16 + lhi * 4 + j;
      int gn = h * 64 + ni * 16 + l15;
      concat[(size_t)gm * 1024 + gn] = f2bf(ctx[ni][j]);
    }
  }

  // zero-fill strictly-upper attn tiles for these 64 rows (nontemporal)
  const int zc0 = (qt + 1) * 64;
  if (zc0 < 2048) {
    const f32x4 z4 = {0.f, 0.f, 0.f, 0.f};
    const int W4 = (2048 - zc0) >> 2;
    f32x4* rowbase = (f32x4*)(attn_bh + (size_t)(qt * 64) * 2048 + zc0);
    for (int rr = 0; rr < 64; rr++) {
      f32x4* rp = rowbase + (size_t)rr * 512;
      for (int cc = tid; cc < W4; cc += 256)
        __builtin_nontemporal_store(z4, &rp[cc]);
    }
  }
}

// ---------------------------------------------------------------------------
extern "C" void kernel_launch(void* const* d_in, const int* in_sizes, int n_in,
                              void* d_out, int out_size, void* d_ws,
                              size_t ws_size, hipStream_t stream) {
  const float* k_in = (const float*)d_in[0];
  const float* v_in = (const float*)d_in[1];
  const float* q_in = (const float*)d_in[2];
  // d_in[3] = mask (unused; causality computed arithmetically)
  const float* wq_w = (const float*)d_in[4];
  const float* wq_b = (const float*)d_in[5];
  const float* wk_w = (const float*)d_in[6];
  const float* wk_b = (const float*)d_in[7];
  const float* wv_w = (const float*)d_in[8];
  const float* wv_b = (const float*)d_in[9];
  const float* wo_w = (const float*)d_in[10];
  const float* wo_b = (const float*)d_in[11];

  char* ws = (char*)d_ws;  // 64 MiB used total
  u16* xq = (u16*)(ws + ((size_t)0 << 20));
  u16* xk = (u16*)(ws + ((size_t)8 << 20));
  u16* xv = (u16*)(ws + ((size_t)16 << 20));
  u16* wqT = (u16*)(ws + ((size_t)24 << 20));
  u16* wkT = (u16*)(ws + ((size_t)26 << 20));
  u16* wvT = (u16*)(ws + ((size_t)28 << 20));
  u16* woT = (u16*)(ws + ((size_t)30 << 20));
  u16* Qh = (u16*)(ws + ((size_t)32 << 20));
  u16* Kh = (u16*)(ws + ((size_t)40 << 20));
  u16* Vt = (u16*)(ws + ((size_t)48 << 20));
  u16* concat = (u16*)(ws + ((size_t)56 << 20));

  float* outp = (float*)d_out;
  float* attnp = outp + (size_t)2 * 2048 * 1024;  // tuple elem 1

  convert_kernel<<<dim3(512, 3), dim3(256), 0, stream>>>(q_in, k_in, v_in, xq,
                                                         xk, xv);
  transw_kernel<<<dim3(16, 16, 4), dim3(256), 0, stream>>>(
      wq_w, wk_w, wv_w, wo_w, wqT, wkT, wvT, woT);
  proj3_kernel<<<dim3(32, 8, 3), dim3(256), 0, stream>>>(
      xq, xk, xv, wqT, wkT, wvT, wq_b, wk_b, wv_b, Qh, Kh, Vt);
  attn_kernel<<<dim3(1024), dim3(256), 0, stream>>>(Qh, Kh, Vt, attnp, concat);
  gemm_out_kernel<<<dim3(32, 8), dim3(256), 0, stream>>>(concat, woT, wo_b,
                                                         outp);
}

// Round 19
// 218.814 us; speedup vs baseline: 1.0372x; 1.0075x over previous
//
#include <hip/hip_runtime.h>
#include <hip/hip_bf16.h>
#include <stdint.h>

typedef __attribute__((ext_vector_type(8))) short bf16x8;
typedef __attribute__((ext_vector_type(8))) unsigned short u16x8;
typedef __attribute__((ext_vector_type(4))) float f32x4;
typedef __attribute__((ext_vector_type(4))) unsigned short u16x4;
typedef unsigned short u16;

// async global->LDS, 16B per lane. LDS dest must be wave-uniform base (+lane*16).
#define GLD16(g, l) __builtin_amdgcn_global_load_lds( \
    (const __attribute__((address_space(1))) unsigned int*)(g), \
    (__attribute__((address_space(3))) unsigned int*)(l), 16, 0, 0)

__device__ __forceinline__ u16 f2bf(float f) {
  union { __hip_bfloat16 h; u16 u; } cv;
  cv.h = __float2bfloat16(f);
  return cv.u;
}

// ---------------------------------------------------------------------------
// fused prep: blocks [0,1536) = f32->bf16 convert of q,k,v (512 blocks each);
// blocks [1536,2560) = weight transpose+convert (256 blocks per weight).
// Single launch replaces the convert + transw pair (saves one dispatch).
// ---------------------------------------------------------------------------
__global__ __launch_bounds__(256) void prep_kernel(
    const float* __restrict__ q_in, const float* __restrict__ k_in,
    const float* __restrict__ v_in, const float* __restrict__ w0,
    const float* __restrict__ w1, const float* __restrict__ w2,
    const float* __restrict__ w3, u16* __restrict__ xq, u16* __restrict__ xk,
    u16* __restrict__ xv, u16* __restrict__ o0, u16* __restrict__ o1,
    u16* __restrict__ o2, u16* __restrict__ o3) {
  const int bid = blockIdx.x;
  if (bid < 1536) {
    // ---- activation convert ----
    const int z = bid / 512, bx = bid % 512;
    const float* s = (z == 0) ? q_in : (z == 1) ? k_in : v_in;
    u16* d = (z == 0) ? xq : (z == 1) ? xk : xv;
    const int n4 = (2 * 2048 * 1024) / 4;
    for (int i = bx * 256 + threadIdx.x; i < n4; i += 512 * 256) {
      float4 v = ((const float4*)s)[i];
      u16x4 o = {f2bf(v.x), f2bf(v.y), f2bf(v.z), f2bf(v.w)};
      ((u16x4*)d)[i] = o;
    }
  } else {
    // ---- weight transpose+convert: 256 blocks per weight, 16x16 tiles ----
    __shared__ float t[64][65];
    const int r = bid - 1536;
    const int z = r >> 8, tile = r & 255;
    const int bx = tile & 15, by = tile >> 4;
    const float* w = (z == 0) ? w0 : (z == 1) ? w1 : (z == 2) ? w2 : w3;
    u16* o = (z == 0) ? o0 : (z == 1) ? o1 : (z == 2) ? o2 : o3;
    const int bi = bx * 64, bj = by * 64;
    const int c = threadIdx.x & 63, r0 = threadIdx.x >> 6;
#pragma unroll
    for (int i = 0; i < 16; i++) {
      int rr = r0 + i * 4;
      t[rr][c] = w[(size_t)(bi + rr) * 1024 + bj + c];
    }
    __syncthreads();
#pragma unroll
    for (int i = 0; i < 16; i++) {
      int rr = r0 + i * 4;
      o[(size_t)(bj + rr) * 1024 + bi + c] = f2bf(t[c][rr]);
    }
  }
}

// ---------------------------------------------------------------------------
// shared GEMM mainloop: C[128x128] = A[M][1024] @ Bt[1024][1024]^T-rows
// ---------------------------------------------------------------------------
static __device__ __forceinline__ void gemm_mainloop(
    const u16* __restrict__ A, const u16* __restrict__ Bt, int bm, int bn,
    u16* Ash, u16* Bsh, f32x4 (&acc)[4][4]) {
  const int tid = threadIdx.x;
  const int wave = tid >> 6, lane = tid & 63;
  const int wm = (wave >> 1) * 64, wn = (wave & 1) * 64;
  const f32x4 vzero = {0.f, 0.f, 0.f, 0.f};
#pragma unroll
  for (int mi = 0; mi < 4; mi++)
#pragma unroll
    for (int ni = 0; ni < 4; ni++) acc[mi][ni] = vzero;

  for (int k0 = 0; k0 < 1024; k0 += 64) {
    __syncthreads();
#pragma unroll
    for (int i = 0; i < 4; i++) {
      int t = i * 256 + tid;
      int row = t >> 3;
      int colb = ((t & 7) * 16) ^ ((row & 7) << 4);
      GLD16((const char*)A + ((size_t)(bm + row) * 1024 + k0) * 2 + colb,
            (char*)Ash + (i * 256 + wave * 64) * 16);
    }
#pragma unroll
    for (int i = 0; i < 4; i++) {
      int t = i * 256 + tid;
      int row = t >> 3;
      int colb = ((t & 7) * 16) ^ ((row & 7) << 4);
      GLD16((const char*)Bt + ((size_t)(bn + row) * 1024 + k0) * 2 + colb,
            (char*)Bsh + (i * 256 + wave * 64) * 16);
    }
    __syncthreads();
#pragma unroll
    for (int kk = 0; kk < 2; kk++) {
      const int d0 = kk * 32 + (lane >> 4) * 8;
      bf16x8 af[4], bv[4];
#pragma unroll
      for (int mi = 0; mi < 4; mi++) {
        int r = wm + mi * 16 + (lane & 15);
        af[mi] = *(const bf16x8*)((const char*)Ash + r * 128 +
                                  ((d0 * 2) ^ ((r & 7) << 4)));
      }
#pragma unroll
      for (int ni = 0; ni < 4; ni++) {
        int r = wn + ni * 16 + (lane & 15);
        bv[ni] = *(const bf16x8*)((const char*)Bsh + r * 128 +
                                  ((d0 * 2) ^ ((r & 7) << 4)));
      }
#pragma unroll
      for (int mi = 0; mi < 4; mi++)
#pragma unroll
        for (int ni = 0; ni < 4; ni++)
          acc[mi][ni] = __builtin_amdgcn_mfma_f32_16x16x32_bf16(
              af[mi], bv[ni], acc[mi][ni], 0, 0, 0);
    }
  }
}

// ---------------------------------------------------------------------------
// fused q/k/v projection GEMM. grid (32, 8, 3). z=0/1: coalesced [4096][1024]
// epilogue to Qh/Kh. z=2: C-tile transposed through a 34KB LDS buffer
// (aliased over Ash/Bsh, dead post-mainloop) and written DIRECTLY to
// Vt [(b*16+h)*64+d][s] as 256B-contiguous segments.
// ---------------------------------------------------------------------------
__global__ __launch_bounds__(256) void proj3_kernel(
    const u16* __restrict__ xq, const u16* __restrict__ xk,
    const u16* __restrict__ xv, const u16* __restrict__ wqT,
    const u16* __restrict__ wkT, const u16* __restrict__ wvT,
    const float* __restrict__ bq, const float* __restrict__ bk,
    const float* __restrict__ bv, u16* __restrict__ Qh, u16* __restrict__ Kh,
    u16* __restrict__ Vt) {
  __shared__ char smem[34816];  // mainloop: Ash(16K)+Bsh(16K); epi: T 128x136
  u16* Ash = (u16*)smem;
  u16* Bsh = Ash + 8192;
  const int z = blockIdx.z;
  const u16* A = (z == 0) ? xq : (z == 1) ? xk : xv;
  const u16* Bt = (z == 0) ? wqT : (z == 1) ? wkT : wvT;
  const float* bias = (z == 0) ? bq : (z == 1) ? bk : bv;
  const int bm = blockIdx.x * 128, bn = blockIdx.y * 128;
  const int tid = threadIdx.x, wave = tid >> 6, lane = tid & 63;
  const int l15 = lane & 15, lhi = lane >> 4;
  const int wm = (wave >> 1) * 64, wn = (wave & 1) * 64;
  f32x4 acc[4][4];
  gemm_mainloop(A, Bt, bm, bn, Ash, Bsh, acc);

  if (z < 2) {
    u16* o = (z == 0) ? Qh : Kh;
#pragma unroll
    for (int ni = 0; ni < 4; ni++) {
      int gn = bn + wn + ni * 16 + l15;
      float bb = bias[gn];
#pragma unroll
      for (int mi = 0; mi < 4; mi++) {
#pragma unroll
        for (int j = 0; j < 4; j++) {
          int gm = bm + wm + mi * 16 + lhi * 4 + j;
          o[(size_t)gm * 1024 + gn] = f2bf(acc[mi][ni][j] + bb);
        }
      }
    }
  } else {
    // ---- z==2: transpose C through LDS, write Vt coalesced ----
    __syncthreads();  // all waves done reading Ash/Bsh
    u16* T = (u16*)smem;  // [128 gn-rows][136 gm-cols] u16 (272B rows)
#pragma unroll
    for (int ni = 0; ni < 4; ni++) {
      int gnl = wn + ni * 16 + l15;
      float bb = bias[bn + gnl];
#pragma unroll
      for (int mi = 0; mi < 4; mi++) {
        int gml = wm + mi * 16 + lhi * 4;
        u16x4 ov = {f2bf(acc[mi][ni][0] + bb), f2bf(acc[mi][ni][1] + bb),
                    f2bf(acc[mi][ni][2] + bb), f2bf(acc[mi][ni][3] + bb)};
        *(u16x4*)((char*)T + gnl * 272 + gml * 2) = ov;
      }
    }
    __syncthreads();
    const int b = bm >> 11;       // batch of this block's 128 gm-rows
    const int s0 = bm & 2047;     // s-coordinate base
#pragma unroll
    for (int i = 0; i < 8; i++) {
      int t = i * 256 + tid;
      int dl = t >> 4, c = t & 15;  // row gn-local, 16B chunk in s
      u16x8 v = *(const u16x8*)((const char*)T + dl * 272 + c * 16);
      *(u16x8*)(Vt + (size_t)(b * 1024 + bn + dl) * 2048 + s0 + c * 8) = v;
    }
  }
}

// ---------------------------------------------------------------------------
// output GEMM: out = concat @ woT + wo_b, f32. grid (32, 8)
// ---------------------------------------------------------------------------
__global__ __launch_bounds__(256) void gemm_out_kernel(
    const u16* __restrict__ A, const u16* __restrict__ Bt,
    const float* __restrict__ bias, float* __restrict__ out) {
  __shared__ u16 Ash[128 * 64], Bsh[128 * 64];
  const int bm = blockIdx.x * 128, bn = blockIdx.y * 128;
  f32x4 acc[4][4];
  gemm_mainloop(A, Bt, bm, bn, Ash, Bsh, acc);
  const int lane = threadIdx.x & 63, wave = threadIdx.x >> 6;
  const int wm = (wave >> 1) * 64, wn = (wave & 1) * 64;
#pragma unroll
  for (int ni = 0; ni < 4; ni++) {
    int gn = bn + wn + ni * 16 + (lane & 15);
    float bb = bias[gn];
#pragma unroll
    for (int mi = 0; mi < 4; mi++) {
#pragma unroll
      for (int j = 0; j < 4; j++) {
        int gm = bm + wm + mi * 16 + (lane >> 4) * 4 + j;
        out[(size_t)gm * 1024 + gn] = acc[mi][ni][j] + bb;
      }
    }
  }
}

// ---------------------------------------------------------------------------
// causal attention — R11/R15 config (best): one q-tile/block, grid 1024 (3
// blocks/CU -> LPT backfill; 4/CU kills it), dbuf prefetch, f32 P staging in
// LDS, coalesced NT attn stores (NT required), counted-vmcnt barrier in
// pass B, NT zero-fill tail.
// ---------------------------------------------------------------------------
__global__ __launch_bounds__(256) void attn_kernel(
    const u16* __restrict__ Qh, const u16* __restrict__ Kh,
    const u16* __restrict__ Vt, float* __restrict__ attn,
    u16* __restrict__ concat) {
  const int bid = blockIdx.x;
  const int xcd = bid & 7;
  const int r = bid >> 3;              // 0..127 within XCD, ~dispatch order
  const int qt = 31 - (r & 31);        // LPT: largest q-tiles first
  const int hb = xcd * 4 + (r >> 5);   // 4 (b,h) pairs per XCD
  const int h = hb & 15, b = hb >> 4;
  const int tid = threadIdx.x, wave = tid >> 6, lane = tid & 63;
  const int l15 = lane & 15, lhi = lane >> 4;
  const f32x4 vzero = {0.f, 0.f, 0.f, 0.f};

  __shared__ u16 Ksh[2][64 * 64], Vsh[2][64 * 64];
  __shared__ float Psf[4][1024];  // per-wave 16x64 f32, XOR-swizzled
  char* Pwc = (char*)Psf[wave];

  const u16* Kbase = Kh + (size_t)(b * 2048) * 1024 + h * 64;
  const u16* Vbase = Vt + (size_t)(b * 16 + h) * 64 * 2048;
  float* attn_bh = attn + (size_t)(b * 16 + h) * 2048 * 2048;

  auto stageK = [&](u16* dst, int kt) {
#pragma unroll
    for (int i = 0; i < 2; i++) {
      int t = i * 256 + tid;
      int row = t >> 3;
      int colb = ((t & 7) * 16) ^ ((row & 7) << 4);
      GLD16((const char*)(Kbase + (size_t)(kt * 64 + row) * 1024) + colb,
            (char*)dst + (i * 256 + wave * 64) * 16);
    }
  };
  auto stageV = [&](u16* dst, int kt) {
#pragma unroll
    for (int i = 0; i < 2; i++) {
      int t = i * 256 + tid;
      int row = t >> 3;
      int colb = ((t & 7) * 16) ^ ((row & 7) << 4);
      GLD16((const char*)(Vbase + (size_t)row * 2048 + kt * 64) + colb,
            (char*)dst + (i * 256 + wave * 64) * 16);
    }
  };
  auto qkt = [&](const u16* Kbuf, const bf16x8* qf, f32x4* sacc) {
#pragma unroll
    for (int ni = 0; ni < 4; ni++) sacc[ni] = vzero;
    __builtin_amdgcn_s_setprio(1);
#pragma unroll
    for (int kk = 0; kk < 2; kk++) {
      const int d0 = kk * 32 + lhi * 8;
#pragma unroll
      for (int ni = 0; ni < 4; ni++) {
        int r2 = ni * 16 + l15;
        bf16x8 kf = *(const bf16x8*)((const char*)Kbuf + r2 * 128 +
                                     ((d0 * 2) ^ ((r2 & 7) << 4)));
        sacc[ni] = __builtin_amdgcn_mfma_f32_16x16x32_bf16(qf[kk], kf,
                                                           sacc[ni], 0, 0, 0);
      }
    }
    __builtin_amdgcn_s_setprio(0);
  };

  const u16* Qrow =
      Qh + (size_t)(b * 2048 + qt * 64 + wave * 16 + l15) * 1024 + h * 64;
  bf16x8 qf[2];
  qf[0] = *(const bf16x8*)(Qrow + lhi * 8);
  qf[1] = *(const bf16x8*)(Qrow + 32 + lhi * 8);

  // ---- pass A: row sums (double-buffered K prefetch) ----
  float srow[4] = {0.f, 0.f, 0.f, 0.f};
  stageK(Ksh[0], 0);
  __syncthreads();  // drains vmcnt
  int cur = 0;
  for (int kt = 0; kt <= qt; kt++) {
    if (kt < qt) stageK(Ksh[cur ^ 1], kt + 1);
    f32x4 sacc[4];
    qkt(Ksh[cur], qf, sacc);
#pragma unroll
    for (int j = 0; j < 4; j++) {
      const int gi = qt * 64 + wave * 16 + lhi * 4 + j;
      float ps = 0.f;
#pragma unroll
      for (int ni = 0; ni < 4; ni++) {
        int gj = kt * 64 + ni * 16 + l15;
        float l = fminf(sacc[ni][j] * 0.125f, 60.f);
        ps += (gj > gi) ? 0.f : __expf(l);
      }
#pragma unroll
      for (int dd = 1; dd < 16; dd <<= 1) ps += __shfl_xor(ps, dd, 16);
      srow[j] += ps;
    }
    __syncthreads();  // prefetch landed + all waves done with Ksh[cur]
    cur ^= 1;
  }
  float rs[4];
#pragma unroll
  for (int j = 0; j < 4; j++) rs[j] = 1.0f / srow[j];

  // ---- pass B: recompute, stage P in LDS, coalesced attn store, PV ----
  f32x4 ctx[4];
#pragma unroll
  for (int ni = 0; ni < 4; ni++) ctx[ni] = vzero;
  stageK(Ksh[0], 0);
  stageV(Vsh[0], 0);
  __syncthreads();
  cur = 0;
  for (int kt = 0; kt <= qt; kt++) {
    if (kt < qt) {
      stageK(Ksh[cur ^ 1], kt + 1);  // 2 GLD16
      stageV(Vsh[cur ^ 1], kt + 1);  // 2 GLD16
    }
    f32x4 sacc[4];
    qkt(Ksh[cur], qf, sacc);
    // softmax -> P staged to per-wave f32 LDS (swizzled)
#pragma unroll
    for (int j = 0; j < 4; j++) {
      const int riw = lhi * 4 + j;
      const int gi = qt * 64 + wave * 16 + riw;
#pragma unroll
      for (int ni = 0; ni < 4; ni++) {
        const int cj = ni * 16 + l15;
        const int gj = kt * 64 + cj;
        float l = fminf(sacc[ni][j] * 0.125f, 60.f);
        float p = (gj > gi) ? 0.f : __expf(l) * rs[j];
        *(float*)(Pwc + ((riw * 256 + cj * 4) ^ ((riw & 7) << 4))) = p;
      }
    }
    // intra-wave only: P writes must land before reads
    asm volatile("s_waitcnt lgkmcnt(0)" ::: "memory");
    __builtin_amdgcn_sched_barrier(0);
    // coalesced attn store: 4 dwordx4 NT stores, 256B/row segments
#pragma unroll
    for (int s = 0; s < 4; s++) {
      const int row = s * 4 + lhi;
      const int gi = qt * 64 + wave * 16 + row;
      f32x4 pv4 =
          *(const f32x4*)(Pwc + ((row * 256 + l15 * 16) ^ ((row & 7) << 4)));
      __builtin_nontemporal_store(
          pv4, (f32x4*)(attn_bh + (size_t)gi * 2048 + kt * 64 + l15 * 4));
    }
    // PV: read P rows from f32 LDS, convert to bf16 in-register
    __builtin_amdgcn_s_setprio(1);
#pragma unroll
    for (int kk = 0; kk < 2; kk++) {
      const int s0 = kk * 32 + lhi * 8;
      f32x4 pa = *(const f32x4*)(Pwc +
                                 ((l15 * 256 + s0 * 4) ^ ((l15 & 7) << 4)));
      f32x4 pb = *(const f32x4*)(
          Pwc + ((l15 * 256 + s0 * 4 + 16) ^ ((l15 & 7) << 4)));
      bf16x8 pf;
      pf[0] = (short)f2bf(pa.x); pf[1] = (short)f2bf(pa.y);
      pf[2] = (short)f2bf(pa.z); pf[3] = (short)f2bf(pa.w);
      pf[4] = (short)f2bf(pb.x); pf[5] = (short)f2bf(pb.y);
      pf[6] = (short)f2bf(pb.z); pf[7] = (short)f2bf(pb.w);
#pragma unroll
      for (int ni = 0; ni < 4; ni++) {
        int vr = ni * 16 + l15;
        bf16x8 vf = *(const bf16x8*)((const char*)Vsh[cur] + vr * 128 +
                                     ((s0 * 2) ^ ((vr & 7) << 4)));
        ctx[ni] = __builtin_amdgcn_mfma_f32_16x16x32_bf16(pf, vf, ctx[ni],
                                                          0, 0, 0);
      }
    }
    __builtin_amdgcn_s_setprio(0);
    // counted barrier: wait only the 4 prefetch loads (oldest in-order);
    // the 4 attn stores (issued after them) may stay in flight.
    asm volatile("s_waitcnt vmcnt(4) lgkmcnt(0)" ::: "memory");
    __builtin_amdgcn_sched_barrier(0);
    __builtin_amdgcn_s_barrier();
    cur ^= 1;
  }

  // ctx -> concat (bf16, standard [4096][1024] layout)
#pragma unroll
  for (int ni = 0; ni < 4; ni++) {
#pragma unroll
    for (int j = 0; j < 4; j++) {
      int gm = b * 2048 + qt * 64 + wave * 16 + lhi * 4 + j;
      int gn = h * 64 + ni * 16 + l15;
      concat[(size_t)gm * 1024 + gn] = f2bf(ctx[ni][j]);
    }
  }

  // zero-fill strictly-upper attn tiles for these 64 rows (nontemporal)
  const int zc0 = (qt + 1) * 64;
  if (zc0 < 2048) {
    const f32x4 z4 = {0.f, 0.f, 0.f, 0.f};
    const int W4 = (2048 - zc0) >> 2;
    f32x4* rowbase = (f32x4*)(attn_bh + (size_t)(qt * 64) * 2048 + zc0);
    for (int rr = 0; rr < 64; rr++) {
      f32x4* rp = rowbase + (size_t)rr * 512;
      for (int cc = tid; cc < W4; cc += 256)
        __builtin_nontemporal_store(z4, &rp[cc]);
    }
  }
}

// ---------------------------------------------------------------------------
extern "C" void kernel_launch(void* const* d_in, const int* in_sizes, int n_in,
                              void* d_out, int out_size, void* d_ws,
                              size_t ws_size, hipStream_t stream) {
  const float* k_in = (const float*)d_in[0];
  const float* v_in = (const float*)d_in[1];
  const float* q_in = (const float*)d_in[2];
  // d_in[3] = mask (unused; causality computed arithmetically)
  const float* wq_w = (const float*)d_in[4];
  const float* wq_b = (const float*)d_in[5];
  const float* wk_w = (const float*)d_in[6];
  const float* wk_b = (const float*)d_in[7];
  const float* wv_w = (const float*)d_in[8];
  const float* wv_b = (const float*)d_in[9];
  const float* wo_w = (const float*)d_in[10];
  const float* wo_b = (const float*)d_in[11];

  char* ws = (char*)d_ws;  // 64 MiB used total
  u16* xq = (u16*)(ws + ((size_t)0 << 20));
  u16* xk = (u16*)(ws + ((size_t)8 << 20));
  u16* xv = (u16*)(ws + ((size_t)16 << 20));
  u16* wqT = (u16*)(ws + ((size_t)24 << 20));
  u16* wkT = (u16*)(ws + ((size_t)26 << 20));
  u16* wvT = (u16*)(ws + ((size_t)28 << 20));
  u16* woT = (u16*)(ws + ((size_t)30 << 20));
  u16* Qh = (u16*)(ws + ((size_t)32 << 20));
  u16* Kh = (u16*)(ws + ((size_t)40 << 20));
  u16* Vt = (u16*)(ws + ((size_t)48 << 20));
  u16* concat = (u16*)(ws + ((size_t)56 << 20));

  float* outp = (float*)d_out;
  float* attnp = outp + (size_t)2 * 2048 * 1024;  // tuple elem 1

  prep_kernel<<<dim3(2560), dim3(256), 0, stream>>>(
      q_in, k_in, v_in, wq_w, wk_w, wv_w, wo_w, xq, xk, xv, wqT, wkT, wvT,
      woT);
  proj3_kernel<<<dim3(32, 8, 3), dim3(256), 0, stream>>>(
      xq, xk, xv, wqT, wkT, wvT, wq_b, wk_b, wv_b, Qh, Kh, Vt);
  attn_kernel<<<dim3(1024), dim3(256), 0, stream>>>(Qh, Kh, Vt, attnp, concat);
  gemm_out_kernel<<<dim3(32, 8), dim3(256), 0, stream>>>(concat, woT, wo_b,
                                                         outp);
}